// Round 7
// baseline (326.546 us; speedup 1.0000x reference)
//
#include <hip/hip_runtime.h>

#define NB 4
#define NS 1024
#define NH 256
#define NR 65536
#define NF 768
#define NK 512

typedef __attribute__((ext_vector_type(8))) short bf16x8;
typedef __attribute__((ext_vector_type(4))) float f32x4;
typedef __attribute__((ext_vector_type(16))) float f32x16;

static __device__ __forceinline__ unsigned short f2bf(float f) {
  unsigned int u = __builtin_bit_cast(unsigned int, f);
  u += 0x7FFFu + ((u >> 16) & 1u);   // RTNE
  return (unsigned short)(u >> 16);
}

// HW packed convert: lo = bf16(a), hi = bf16(b), RTNE.
static __device__ __forceinline__ unsigned cvt_pk(float a, float b) {
  unsigned r;
  asm("v_cvt_pk_bf16_f32 %0, %1, %2" : "=v"(r) : "v"(a), "v"(b));
  return r;
}

// Raw barrier: lgkmcnt(0) only -- does NOT drain vmcnt, so in-flight global
// loads survive the barrier.
#define BARRIER()                                            \
  do {                                                       \
    asm volatile("s_waitcnt lgkmcnt(0)" ::: "memory");       \
    __builtin_amdgcn_s_barrier();                            \
    asm volatile("" ::: "memory");                           \
  } while (0)

// Combined prep for 32x32x16 fragments:
// blocks [0,192) pack W1, [192,288) pack W2, block 288 detects id width.
__global__ void prep_all(const float* __restrict__ w1, const float* __restrict__ w2,
                         const int* __restrict__ ids,
                         unsigned short* __restrict__ w1f,
                         unsigned short* __restrict__ w2f,
                         int* __restrict__ flag) {
  int bid = blockIdx.x;
  if (bid < 192) {
    // W1F unit u = ((c*4 + w)*32 + s)*64 + lane holds
    // W1[k = s*16 + (lane>>5)*8 + j][n1 = c*128 + w*32 + (lane&31)], j=0..7
    int t = bid * 256 + threadIdx.x;          // 49152 units
    int l = t & 63;
    int s = (t >> 6) & 31;
    int w = (t >> 11) & 3;
    int c = t >> 13;
    int n1 = c * 128 + w * 32 + (l & 31);
    int k0 = s * 16 + (l >> 5) * 8;
    uint4 pk;
    unsigned short v[8];
#pragma unroll
    for (int j = 0; j < 8; ++j) v[j] = f2bf(w1[(size_t)(k0 + j) * NF + n1]);
    pk.x = v[0] | ((unsigned)v[1] << 16);
    pk.y = v[2] | ((unsigned)v[3] << 16);
    pk.z = v[4] | ((unsigned)v[5] << 16);
    pk.w = v[6] | ((unsigned)v[7] << 16);
    *(uint4*)(w1f + (size_t)t * 8) = pk;
  } else if (bid < 288) {
    // W2F unit u = (((w*2 + nt)*6 + c)*8 + ks)*64 + lane holds
    // W2[k2 = c*128 + ks*16 + (lane>>5)*8 + j][n2 = w*64 + nt*32 + (lane&31)]
    int t = (bid - 192) * 256 + threadIdx.x;  // 24576 units
    int l = t & 63;
    int ks = (t >> 6) & 7;
    int rest = t >> 9;                        // (w*2+nt)*6 + c
    int c = rest % 6;
    int wn = rest / 6;                        // w*2 + nt
    int nt = wn & 1;
    int w = wn >> 1;
    int n2 = w * 64 + nt * 32 + (l & 31);
    int k2 = c * 128 + ks * 16 + (l >> 5) * 8;
    uint4 pk;
    unsigned short v[8];
#pragma unroll
    for (int j = 0; j < 8; ++j) v[j] = f2bf(w2[(size_t)(k2 + j) * NH + n2]);
    pk.x = v[0] | ((unsigned)v[1] << 16);
    pk.y = v[2] | ((unsigned)v[3] << 16);
    pk.z = v[4] | ((unsigned)v[5] << 16);
    pk.w = v[6] | ((unsigned)v[7] << 16);
    *(uint4*)(w2f + (size_t)t * 8) = pk;
  } else {
    __shared__ int anynz;
    if (threadIdx.x == 0) anynz = 0;
    __syncthreads();
    int acc = 0;
    for (int i = threadIdx.x; i < 8192; i += 256) acc |= ids[2 * i + 1];
    if (acc != 0) atomicOr(&anynz, 1);
    __syncthreads();
    if (threadIdx.x == 0) flag[0] = (anynz == 0) ? 1 : 0;  // 1 => int64
  }
}

// Fused: gather -> GEMM1(relu,+b1) -> GEMM2(+b2), 64 rows/block, 4 waves.
// 32x32x16 MFMA everywhere: half the MFMA instructions, +20% pipe rate.
// C/D layout (m74/m101): col = lane&31, row = (reg&3)+8*(reg>>2)+4*(lane>>5).
__global__ __launch_bounds__(256, 2)
void fused_relffn(const float* __restrict__ span, const int* __restrict__ ids,
                  const float* __restrict__ b1, const float* __restrict__ b2,
                  const unsigned short* __restrict__ w1f,
                  const unsigned short* __restrict__ w2f,
                  const int* __restrict__ flagp, float* __restrict__ out) {
  __shared__ __align__(16) unsigned short As[64 * 512];  // 64 KB, swizzled
  __shared__ __align__(16) unsigned short Hs[64 * 128];  // 16 KB, swizzled

  const int tid = threadIdx.x;
  const int blk = blockIdx.x;
  const int bb = blk >> 10;              // batch
  const int r0 = (blk & 1023) << 6;      // first relation row
  const int lane = tid & 63;
  const int w = tid >> 6;                // wave 0..3
  const int l31 = lane & 31;
  const int l5 = lane >> 5;              // 0..1
  const int is64 = flagp[0];

  // Packed W1 base: + c*65536 per chunk, + s*512 per k-step.
  const unsigned short* w1base = w1f + w * 16384 + lane * 8;
  // Packed W2 base: + nt*24576 + c*4096 + ks*512.
  const unsigned short* w2base = w2f + w * 49152 + lane * 8;

  // ---- gather A tile: ids preloaded, then unrolled load/convert ----
  {
    const long pair0 = ((long)bb * NR + r0) * 2;
    int idv[16];
#pragma unroll
    for (int j = 0; j < 16; ++j) {
      int g = tid + j * 256;
      int row = g >> 6;
      int kc = g & 63;
      long pidx = pair0 + row * 2 + (kc >> 5);
      idv[j] = is64 ? ids[pidx * 2] : ids[pidx];
    }
#pragma unroll
    for (int j = 0; j < 16; ++j) {
      int g = tid + j * 256;
      int row = g >> 6;
      int kc = g & 63;
      const float* src = span + ((size_t)bb * NS + idv[j]) * NH + (kc & 31) * 8;
      float4 v0 = *(const float4*)src;
      float4 v1 = *(const float4*)(src + 4);
      uint4 pk;
      pk.x = cvt_pk(v0.x, v0.y);
      pk.y = cvt_pk(v0.z, v0.w);
      pk.z = cvt_pk(v1.x, v1.y);
      pk.w = cvt_pk(v1.z, v1.w);
      int idx = row * 512 + ((kc * 8) ^ ((row & 7) << 3));  // XOR swizzle
      *(uint4*)&As[idx] = pk;
    }
  }
  BARRIER();

  f32x16 acc2[2][2];   // [mi][nt]
#pragma unroll
  for (int mi = 0; mi < 2; ++mi)
#pragma unroll
    for (int nt = 0; nt < 2; ++nt)
#pragma unroll
      for (int r = 0; r < 16; ++r) acc2[mi][nt][r] = 0.f;

  for (int cp = 0; cp < 3; ++cp) {
    const int ca = cp * 2, cb = ca + 1;
    const unsigned short* wpa = w1base + ca * 65536;
    const unsigned short* wpb = w1base + cb * 65536;

    // ---- GEMM1 pair: one af sweep (32 k-steps) feeds chunks ca and cb ----
    f32x16 acc1a[2], acc1b[2];   // [mi]
#pragma unroll
    for (int mi = 0; mi < 2; ++mi)
#pragma unroll
      for (int r = 0; r < 16; ++r) { acc1a[mi][r] = 0.f; acc1b[mi][r] = 0.f; }

    bf16x8 wfa[2], wfb[2];       // rolling 2-deep weight prefetch
    wfa[0] = *(const bf16x8*)(wpa);
    wfa[1] = *(const bf16x8*)(wpa + 512);
    wfb[0] = *(const bf16x8*)(wpb);
    wfb[1] = *(const bf16x8*)(wpb + 512);
    bf16x8 afp[2][2];            // af double buffer [buf][mi]
#pragma unroll
    for (int mi = 0; mi < 2; ++mi) {
      int row = mi * 32 + l31;
      afp[0][mi] = *(const bf16x8*)&As[row * 512 + ((l5 * 8) ^ ((row & 7) << 3))];
    }

#pragma unroll
    for (int s = 0; s < 32; ++s) {
      const int cur = s & 1;
      if (s < 31) {   // prefetch next step's af
#pragma unroll
        for (int mi = 0; mi < 2; ++mi) {
          int row = mi * 32 + l31;
          int col = (s + 1) * 16 + l5 * 8;
          afp[cur ^ 1][mi] = *(const bf16x8*)&As[row * 512 + (col ^ ((row & 7) << 3))];
        }
      }
      bf16x8 ca_ = wfa[cur], cb_ = wfb[cur];
      if (s < 30) {   // refill wf slot with s+2
        wfa[cur] = *(const bf16x8*)(wpa + (s + 2) * 512);
        wfb[cur] = *(const bf16x8*)(wpb + (s + 2) * 512);
      }
      __builtin_amdgcn_s_setprio(1);
#pragma unroll
      for (int mi = 0; mi < 2; ++mi) {
        acc1a[mi] = __builtin_amdgcn_mfma_f32_32x32x16_bf16(ca_, afp[cur][mi], acc1a[mi], 0, 0, 0);
        acc1b[mi] = __builtin_amdgcn_mfma_f32_32x32x16_bf16(cb_, afp[cur][mi], acc1b[mi], 0, 0, 0);
      }
      __builtin_amdgcn_s_setprio(0);
    }

    // ---- per chunk: pack -> GEMM2 ----
#pragma unroll
    for (int half = 0; half < 2; ++half) {
      const int c = half ? cb : ca;
      const unsigned short* w2p = w2base + c * 4096;
      // vf prologue issued before the barriers: stays in flight (lgkm-only).
      bf16x8 vf2[2][2];   // [depth][nt]
#pragma unroll
      for (int nt = 0; nt < 2; ++nt) {
        vf2[0][nt] = *(const bf16x8*)(w2p + nt * 24576);
        vf2[1][nt] = *(const bf16x8*)(w2p + nt * 24576 + 512);
      }

      BARRIER();   // prior GEMM2's Hs reads done before overwrite
      // bias + relu + pack. Lane's 16 regs = 4 groups of 4 consecutive n1.
#pragma unroll
      for (int mi = 0; mi < 2; ++mi) {
        const int m = mi * 32 + l31;
#pragma unroll
        for (int g = 0; g < 4; ++g) {
          int nl = w * 32 + g * 8 + 4 * l5;         // n1 within chunk
          float4 bv = *(const float4*)(b1 + c * 128 + nl);
          f32x16 a = half ? acc1b[mi] : acc1a[mi];
          float x0 = fmaxf(a[4 * g + 0] + bv.x, 0.0f);
          float x1 = fmaxf(a[4 * g + 1] + bv.y, 0.0f);
          float x2 = fmaxf(a[4 * g + 2] + bv.z, 0.0f);
          float x3 = fmaxf(a[4 * g + 3] + bv.w, 0.0f);
          uint2 pk;
          pk.x = cvt_pk(x0, x1);
          pk.y = cvt_pk(x2, x3);
          *(uint2*)&Hs[m * 128 + (nl ^ ((m & 7) << 3))] = pk;
        }
      }
      BARRIER();
      // ---- GEMM2: 8 k-steps, hf double-buffered, vf rolling 2-deep ----
      bf16x8 hfp[2][2];   // [buf][mi]
#pragma unroll
      for (int mi = 0; mi < 2; ++mi) {
        int row = mi * 32 + l31;
        hfp[0][mi] = *(const bf16x8*)&Hs[row * 128 + ((l5 * 8) ^ ((row & 7) << 3))];
      }
#pragma unroll
      for (int ks = 0; ks < 8; ++ks) {
        const int cur = ks & 1;
        if (ks < 7) {
#pragma unroll
          for (int mi = 0; mi < 2; ++mi) {
            int row = mi * 32 + l31;
            int col = (ks + 1) * 16 + l5 * 8;
            hfp[cur ^ 1][mi] = *(const bf16x8*)&Hs[row * 128 + (col ^ ((row & 7) << 3))];
          }
        }
        bf16x8 v0 = vf2[cur][0], v1 = vf2[cur][1];
        if (ks < 6) {
          vf2[cur][0] = *(const bf16x8*)(w2p + (ks + 2) * 512);
          vf2[cur][1] = *(const bf16x8*)(w2p + 24576 + (ks + 2) * 512);
        }
        __builtin_amdgcn_s_setprio(1);
#pragma unroll
        for (int mi = 0; mi < 2; ++mi) {
          acc2[mi][0] = __builtin_amdgcn_mfma_f32_32x32x16_bf16(v0, hfp[cur][mi], acc2[mi][0], 0, 0, 0);
          acc2[mi][1] = __builtin_amdgcn_mfma_f32_32x32x16_bf16(v1, hfp[cur][mi], acc2[mi][1], 0, 0, 0);
        }
        __builtin_amdgcn_s_setprio(0);
      }
    }
  }

  // ---- epilogue: +b2, float4 stores (4 groups of 4 consecutive n2) ----
#pragma unroll
  for (int mi = 0; mi < 2; ++mi) {
    const int m = mi * 32 + l31;
    float* orow = out + ((size_t)bb * NR + r0 + m) * NH;
#pragma unroll
    for (int nt = 0; nt < 2; ++nt) {
#pragma unroll
      for (int g = 0; g < 4; ++g) {
        int n0 = w * 64 + nt * 32 + g * 8 + 4 * l5;
        float4 bv = *(const float4*)(b2 + n0);
        f32x16 a = acc2[mi][nt];
        float4 o;
        o.x = a[4 * g + 0] + bv.x;
        o.y = a[4 * g + 1] + bv.y;
        o.z = a[4 * g + 2] + bv.z;
        o.w = a[4 * g + 3] + bv.w;
        *(float4*)(orow + n0) = o;
      }
    }
  }
}

extern "C" void kernel_launch(void* const* d_in, const int* in_sizes, int n_in,
                              void* d_out, int out_size, void* d_ws, size_t ws_size,
                              hipStream_t stream) {
  const float* span = (const float*)d_in[0];
  const int* ids = (const int*)d_in[1];
  const float* W1 = (const float*)d_in[2];
  const float* b1 = (const float*)d_in[3];
  const float* W2 = (const float*)d_in[4];
  const float* b2 = (const float*)d_in[5];
  float* out = (float*)d_out;

  char* ws = (char*)d_ws;
  int* flag = (int*)ws;
  unsigned short* w1f = (unsigned short*)(ws + 64);                    // 49152*16B
  unsigned short* w2f = (unsigned short*)(ws + 64 + NF * NK * 2);      // 24576*16B

  prep_all<<<289, 256, 0, stream>>>(W1, W2, ids, w1f, w2f, flag);
  fused_relffn<<<4096, 256, 0, stream>>>(span, ids, b1, b2, w1f, w2f, flag, out);
}